// Round 3
// baseline (512.809 us; speedup 1.0000x reference)
//
#include <hip/hip_runtime.h>

// WindowAttention: x(128,256,512) -> qkv -> windowed attn (epeg conv folded
// into Q; barrier-free reg-resident softmax) -> proj. bf16-MFMA pipeline.
//
// ws layout (bytes):
//   [0)          xbf   33,554,432  (x bf16; REUSED as attnout after gemm_qkv)
//   [33554432)   w1     1,572,864  (qkv_w bf16)
//   [35127296)   w2       524,288  (proj_w bf16)
//   [35651584)   qb    33,554,432  (q scaled (b,h,n,d); conv'd in place)
//   [69206016)   kb    33,554,432  ((b,h,m,d))
//   [102760448)  vb    33,554,432  (V (b,h,n,d); TRANSPOSED IN PLACE to (b,h,d,n) by qv_prep)

typedef unsigned short u16;
typedef unsigned int u32;
typedef __attribute__((ext_vector_type(8))) short short8;   // 8 bf16 (4 VGPRs)
typedef __attribute__((ext_vector_type(4))) float f32x4;

__device__ __forceinline__ u16 f2bf(float f) {
  union { float f; u32 u; } v; v.f = f;
  return (u16)((v.u + 0x7FFFu + ((v.u >> 16) & 1u)) >> 16);  // RNE
}
__device__ __forceinline__ float bf2f(u16 s) {
  union { u32 u; float f; } v; v.u = ((u32)s) << 16;
  return v.f;
}

__device__ __forceinline__ void gl2lds16(const u16* g, u16* l) {
  __builtin_amdgcn_global_load_lds((const __attribute__((address_space(1))) void*)g,
                                   (__attribute__((address_space(3))) void*)l, 16, 0, 0);
}

// fragment cell address (u16 units) with bank-spreading XOR swizzle
__device__ __forceinline__ int fragaddr(int frag, int lane) {
  return (frag * 64 + (lane ^ (frag & 7))) * 8;
}

// ---------------- fp32 -> bf16 conversion ------------------------------------
__global__ __launch_bounds__(256) void cvt_all(
    const float* __restrict__ x, const float* __restrict__ w1f,
    const float* __restrict__ w2f, u16* __restrict__ xo,
    u16* __restrict__ w1o, u16* __restrict__ w2o) {
  const int NX = 4194304, NW1 = 196608, NW2 = 65536;
  int i = blockIdx.x * 256 + threadIdx.x;
  const float* src; u16* dst; int j;
  if (i < NX)                  { src = x;   dst = xo;  j = i; }
  else if (i < NX + NW1)       { src = w1f; dst = w1o; j = i - NX; }
  else if (i < NX + NW1 + NW2) { src = w2f; dst = w2o; j = i - NX - NW1; }
  else return;
  float4 f = ((const float4*)src)[j];
  uint2 o;
  o.x = (u32)f2bf(f.x) | ((u32)f2bf(f.y) << 16);
  o.y = (u32)f2bf(f.z) | ((u32)f2bf(f.w) << 16);
  ((uint2*)dst)[j] = o;
}

// ---------------- shared GEMM core: C[128x128] = A[128xK] * B[128xK]^T -------
template <int KDIM>
__device__ __forceinline__ void gemm_core(const u16* __restrict__ A,
                                          const u16* __restrict__ B,
                                          int m0, int n0,
                                          u16* As, u16* Bs, f32x4 acc[4][4]) {
  int tid = threadIdx.x, wave = tid >> 6, lane = tid & 63;
  int wm = wave >> 1, wn = wave & 1;
  int lr = lane >> 3, lc = (lane & 7) * 8;
  const u16* Ag = A + (size_t)(m0 + wave * 32 + lr) * KDIM + lc;
  const u16* Bg = B + (size_t)(n0 + wave * 32 + lr) * KDIM + lc;
  u16* AsW = As + wave * 32 * 64;
  u16* BsW = Bs + wave * 32 * 64;
  for (int k0 = 0; k0 < KDIM; k0 += 64) {
#pragma unroll
    for (int it = 0; it < 4; ++it) {
      gl2lds16(Ag + k0 + it * 8 * KDIM, AsW + it * 8 * 64);
      gl2lds16(Bg + k0 + it * 8 * KDIM, BsW + it * 8 * 64);
    }
    __syncthreads();
    int q8 = (lane >> 4) * 8;
#pragma unroll
    for (int ks = 0; ks < 64; ks += 32) {
      short8 af[4], bf8[4];
#pragma unroll
      for (int t = 0; t < 4; ++t) {
        af[t]  = *(const short8*)(As + (wm * 64 + t * 16 + (lane & 15)) * 64 + ks + q8);
        bf8[t] = *(const short8*)(Bs + (wn * 64 + t * 16 + (lane & 15)) * 64 + ks + q8);
      }
#pragma unroll
      for (int tm = 0; tm < 4; ++tm)
#pragma unroll
        for (int tn = 0; tn < 4; ++tn)
          acc[tm][tn] = __builtin_amdgcn_mfma_f32_16x16x32_bf16(
              af[tm], bf8[tn], acc[tm][tn], 0, 0, 0);
    }
    __syncthreads();
  }
}

// ---------------- GEMM1: qkv = x @ qkv_w^T + b; scatter q(scaled)/k/v --------
__global__ __launch_bounds__(256) void gemm_qkv(
    const u16* __restrict__ A, const u16* __restrict__ B,
    const float* __restrict__ qkvb, u16* __restrict__ qb,
    u16* __restrict__ kb, u16* __restrict__ vb) {
  __shared__ __align__(16) u16 As[128 * 64];
  __shared__ __align__(16) u16 Bs[128 * 64];
  f32x4 acc[4][4];
#pragma unroll
  for (int a = 0; a < 4; ++a)
#pragma unroll
    for (int c = 0; c < 4; ++c) acc[a][c] = (f32x4){0.f, 0.f, 0.f, 0.f};
  int m0 = blockIdx.x * 128, n0 = blockIdx.y * 128;
  gemm_core<512>(A, B, m0, n0, As, Bs, acc);
  int tid = threadIdx.x, wave = tid >> 6, lane = tid & 63;
  int wm = wave >> 1, wn = wave & 1;
#pragma unroll
  for (int tm = 0; tm < 4; ++tm) {
    int rbase = m0 + wm * 64 + tm * 16 + (lane >> 4) * 4;
#pragma unroll
    for (int tn = 0; tn < 4; ++tn) {
      int c = n0 + wn * 64 + tn * 16 + (lane & 15);
      float bv = qkvb[c];
      int which = c >> 9, cc = c & 511;
      int h = cc >> 6, d = cc & 63;
#pragma unroll
      for (int i = 0; i < 4; ++i) {
        int r = rbase + i;
        int b = r >> 8, n = r & 255;
        float v = acc[tm][tn][i] + bv;
        size_t idx = ((size_t)(b * 8 + h) * 256 + n) * 64 + d;
        if (which == 0)      qb[idx] = f2bf(v * 0.125f);
        else if (which == 1) kb[idx] = f2bf(v);
        else                 vb[idx] = f2bf(v);
      }
    }
  }
}

// ---------------- qv_prep: Q' = Q + conv15_n(Q) in place; V -> V^T in place --
__global__ __launch_bounds__(256, 2) void qv_prep(u16* __restrict__ qb,
                                                  u16* __restrict__ vb,
                                                  const float* __restrict__ pe_w) {
  __shared__ __align__(16) u16 Ql[256 * 72];
  __shared__ __align__(16) u16 Vl[256 * 72];
  __shared__ float w[15];
  int bh = blockIdx.x, h = bh & 7, tid = threadIdx.x;
  const uint4* qs = (const uint4*)(qb + (size_t)bh * 16384);
  const uint4* vs = (const uint4*)(vb + (size_t)bh * 16384);
#pragma unroll
  for (int it = 0; it < 8; ++it) {
    int idx = tid + it * 256;
    int row = idx >> 3, c = (idx & 7) * 8;
    *(uint4*)(Ql + row * 72 + c) = qs[idx];
    *(uint4*)(Vl + row * 72 + c) = vs[idx];
  }
  if (tid < 15) w[tid] = pe_w[h * 15 + tid] + (tid == 7 ? 1.f : 0.f);
  __syncthreads();
  // --- Q conv over n (in place) ---
  {
    int dg = (tid & 15) * 4, nb4 = tid >> 4;
    uint2* dst = (uint2*)(qb + (size_t)bh * 16384);
#pragma unroll
    for (int i = 0; i < 16; ++i) {
      int n = nb4 + i * 16;
      float a0 = 0.f, a1 = 0.f, a2 = 0.f, a3 = 0.f;
#pragma unroll
      for (int t = 0; t < 15; ++t) {
        int nn = n + t - 7;
        if (nn < 0 || nn > 255) continue;
        uint2 rv = *(const uint2*)(Ql + nn * 72 + dg);
        float wt = w[t];
        a0 += wt * bf2f(rv.x & 0xffff); a1 += wt * bf2f(rv.x >> 16);
        a2 += wt * bf2f(rv.y & 0xffff); a3 += wt * bf2f(rv.y >> 16);
      }
      uint2 pv;
      pv.x = (u32)f2bf(a0) | ((u32)f2bf(a1) << 16);
      pv.y = (u32)f2bf(a2) | ((u32)f2bf(a3) << 16);
      dst[(n * 64 + dg) >> 2] = pv;
    }
  }
  // --- V transpose (in place): vb becomes (d, m) ---
  {
    int lane = tid & 63, wv = tid >> 6;   // lane = d
    uint2* dstv = (uint2*)(vb + (size_t)bh * 16384);
#pragma unroll
    for (int it = 0; it < 16; ++it) {
      int m0 = (wv + it * 4) * 4;
      u16 v0 = Vl[(m0 + 0) * 72 + lane];
      u16 v1 = Vl[(m0 + 1) * 72 + lane];
      u16 v2 = Vl[(m0 + 2) * 72 + lane];
      u16 v3 = Vl[(m0 + 3) * 72 + lane];
      uint2 pv;
      pv.x = (u32)v0 | ((u32)v1 << 16);
      pv.y = (u32)v2 | ((u32)v3 << 16);
      dstv[(lane * 256 + m0) >> 2] = pv;
    }
  }
}

// ---------------- attention: 1 wg (512 thr) per (b,h); barrier-free loop -----
// LDS: Kfrag 32K + Vfrag 32K + Ps 10K + bias 3.8K = 77.8K -> 2 wg/CU
__global__ __launch_bounds__(512, 4) void attn_win(
    const u16* __restrict__ qb, const u16* __restrict__ kb,
    const u16* __restrict__ vtb, const float* __restrict__ pe_b,
    const float* __restrict__ rpb, u16* __restrict__ attnout) {
  __shared__ __align__(16) u16 Kf[16384];   // 32 frags (mt,kt), fragment-ordered
  __shared__ __align__(16) u16 Vf[16384];   // 32 frags (dt,km), fragment-ordered
  __shared__ __align__(16) u16 Ps[8 * 640]; // per-wave 16x40 P scratch
  __shared__ float biasl[961];
  __shared__ float pebs;

  int bh = blockIdx.x, b = bh >> 3, h = bh & 7;
  int tid = threadIdx.x, wave = tid >> 6, lane = tid & 63;

  // ---- staging (the only barrier in the kernel) ----
  {
    const uint4* kg = (const uint4*)(kb + (size_t)bh * 16384);
    const uint4* vg = (const uint4*)(vtb + (size_t)bh * 16384);
#pragma unroll
    for (int it = 0; it < 4; ++it) {
      int idx = tid + it * 512;
      // K: (n, k) row-major -> frag (mt = n>>4, kt = k8>>2)
      {
        uint4 val = kg[idx];
        int n = idx >> 3, k8 = idx & 7;
        int frag = (n >> 4) * 2 + (k8 >> 2);
        int lanep = (n & 15) + 16 * (k8 & 3);
        *(uint4*)(Kf + (frag * 64 + (lanep ^ (frag & 7))) * 8) = val;
      }
      // V^T: (d, m) row-major -> frag (dt = d>>4, km = m8>>2)
      {
        uint4 val = vg[idx];
        int d = idx >> 5, m8 = idx & 31;
        int frag = (d >> 4) * 8 + (m8 >> 2);
        int lanep = (d & 15) + 16 * (m8 & 3);
        *(uint4*)(Vf + (frag * 64 + (lanep ^ (frag & 7))) * 8) = val;
      }
    }
    for (int i = tid; i < 961; i += 512) biasl[i] = rpb[i * 8 + h];
    if (tid == 0) pebs = pe_b[h];
  }
  __syncthreads();

  int cx = lane & 15, g = lane >> 4;
  u16* Psw = Ps + wave * 640;

  for (int it2 = 0; it2 < 2; ++it2) {
    int qbase = it2 * 128 + wave * 16;
    // Q A-frags direct from global (L2-resident)
    const u16* qg = qb + (size_t)bh * 16384 + qbase * 64;
    short8 qf0 = *(const short8*)(qg + cx * 64 + g * 8);
    short8 qf1 = *(const short8*)(qg + cx * 64 + 32 + g * 8);

    // ---- QK^T: strip x all 16 m-tiles, S in registers ----
    f32x4 acc[16];
#pragma unroll
    for (int mt = 0; mt < 16; ++mt) acc[mt] = (f32x4){0.f, 0.f, 0.f, 0.f};
#pragma unroll
    for (int mt = 0; mt < 16; ++mt) {
      short8 k0 = *(const short8*)(Kf + fragaddr(mt * 2, lane));
      short8 k1 = *(const short8*)(Kf + fragaddr(mt * 2 + 1, lane));
      acc[mt] = __builtin_amdgcn_mfma_f32_16x16x32_bf16(qf0, k0, acc[mt], 0, 0, 0);
      acc[mt] = __builtin_amdgcn_mfma_f32_16x16x32_bf16(qf1, k1, acc[mt], 0, 0, 0);
    }

    // ---- bias + in-wave softmax (no barriers) ----
    float inv4[4];
#pragma unroll
    for (int i = 0; i < 4; ++i) {
      int qtok = qbase + g * 4 + i;
      int bbase = ((qtok >> 4) + 15) * 31 + (qtok & 15) - cx + 15;
#pragma unroll
      for (int mt = 0; mt < 16; ++mt) acc[mt][i] += pebs + biasl[bbase - 31 * mt];
      float mx = acc[0][i];
#pragma unroll
      for (int mt = 1; mt < 16; ++mt) mx = fmaxf(mx, acc[mt][i]);
      mx = fmaxf(mx, __shfl_xor(mx, 1));
      mx = fmaxf(mx, __shfl_xor(mx, 2));
      mx = fmaxf(mx, __shfl_xor(mx, 4));
      mx = fmaxf(mx, __shfl_xor(mx, 8));
      float s = 0.f;
#pragma unroll
      for (int mt = 0; mt < 16; ++mt) {
        float e = __expf(acc[mt][i] - mx);
        acc[mt][i] = e; s += e;
      }
      s += __shfl_xor(s, 1);
      s += __shfl_xor(s, 2);
      s += __shfl_xor(s, 4);
      s += __shfl_xor(s, 8);
      inv4[i] = 1.f / s;
    }

    // ---- PV via per-wave chunk scratch (LDS ops in-order per wave) ----
    f32x4 oacc[4];
#pragma unroll
    for (int dt = 0; dt < 4; ++dt) oacc[dt] = (f32x4){0.f, 0.f, 0.f, 0.f};
#pragma unroll
    for (int kk = 0; kk < 8; ++kk) {
#pragma unroll
      for (int t2 = 0; t2 < 2; ++t2)
#pragma unroll
        for (int i = 0; i < 4; ++i)
          Psw[(g * 4 + i) * 40 + t2 * 16 + cx] = f2bf(acc[kk * 2 + t2][i] * inv4[i]);
      short8 pa = *(const short8*)(Psw + cx * 40 + g * 8);
#pragma unroll
      for (int dt = 0; dt < 4; ++dt) {
        short8 vf = *(const short8*)(Vf + fragaddr(dt * 8 + kk, lane));
        oacc[dt] = __builtin_amdgcn_mfma_f32_16x16x32_bf16(pa, vf, oacc[dt], 0, 0, 0);
      }
    }

    // ---- epilogue ----
#pragma unroll
    for (int dt = 0; dt < 4; ++dt)
#pragma unroll
      for (int i = 0; i < 4; ++i)
        attnout[((size_t)b * 256 + qbase + g * 4 + i) * 512 + h * 64 + dt * 16 + cx]
            = f2bf(oacc[dt][i]);
  }
}

// ---------------- GEMM2: out = attnout @ proj_w^T + proj_b (fp32 out) --------
__global__ __launch_bounds__(256) void gemm_proj(
    const u16* __restrict__ A, const u16* __restrict__ B,
    const float* __restrict__ pb, float* __restrict__ out) {
  __shared__ __align__(16) u16 As[128 * 64];
  __shared__ __align__(16) u16 Bs[128 * 64];
  f32x4 acc[4][4];
#pragma unroll
  for (int a = 0; a < 4; ++a)
#pragma unroll
    for (int c = 0; c < 4; ++c) acc[a][c] = (f32x4){0.f, 0.f, 0.f, 0.f};
  int m0 = blockIdx.x * 128, n0 = blockIdx.y * 128;
  gemm_core<512>(A, B, m0, n0, As, Bs, acc);
  int tid = threadIdx.x, wave = tid >> 6, lane = tid & 63;
  int wm = wave >> 1, wn = wave & 1;
#pragma unroll
  for (int tm = 0; tm < 4; ++tm) {
    int rbase = m0 + wm * 64 + tm * 16 + (lane >> 4) * 4;
#pragma unroll
    for (int tn = 0; tn < 4; ++tn) {
      int c = n0 + wn * 64 + tn * 16 + (lane & 15);
      float bv = pb[c];
#pragma unroll
      for (int i = 0; i < 4; ++i)
        out[(size_t)(rbase + i) * 512 + c] = acc[tm][tn][i] + bv;
    }
  }
}

extern "C" void kernel_launch(void* const* d_in, const int* in_sizes, int n_in,
                              void* d_out, int out_size, void* d_ws, size_t ws_size,
                              hipStream_t stream) {
  const float* x      = (const float*)d_in[0];
  const float* qkv_w  = (const float*)d_in[1];
  const float* qkv_b  = (const float*)d_in[2];
  const float* pe_w   = (const float*)d_in[3];
  const float* pe_b   = (const float*)d_in[4];
  const float* rpb    = (const float*)d_in[5];
  const float* proj_w = (const float*)d_in[6];
  const float* proj_b = (const float*)d_in[7];
  float* out = (float*)d_out;
  char* ws = (char*)d_ws;

  size_t off = 0;
  u16* xbf = (u16*)(ws + off); off += (size_t)16777216 * 2;  // also attnout
  u16* w1  = (u16*)(ws + off); off += (size_t)786432 * 2;
  u16* w2  = (u16*)(ws + off); off += (size_t)262144 * 2;
  u16* qb  = (u16*)(ws + off); off += (size_t)16777216 * 2;
  u16* kb  = (u16*)(ws + off); off += (size_t)16777216 * 2;
  u16* vb  = (u16*)(ws + off); off += (size_t)16777216 * 2;

  hipLaunchKernelGGL(cvt_all, dim3(17408), dim3(256), 0, stream,
                     x, qkv_w, proj_w, xbf, w1, w2);
  hipLaunchKernelGGL(gemm_qkv, dim3(256, 12), dim3(256), 0, stream,
                     xbf, w1, qkv_b, qb, kb, vb);
  hipLaunchKernelGGL(qv_prep, dim3(1024), dim3(256), 0, stream, qb, vb, pe_w);
  hipLaunchKernelGGL(attn_win, dim3(1024), dim3(512), 0, stream,
                     qb, kb, vb, pe_b, rpb, xbf);
  hipLaunchKernelGGL(gemm_proj, dim3(256, 4), dim3(256), 0, stream,
                     xbf, w2, proj_b, out);
}

// Round 4
// 358.234 us; speedup vs baseline: 1.4315x; 1.4315x over previous
//
#include <hip/hip_runtime.h>

// WindowAttention: x(128,256,512) -> qkv -> windowed attn (epeg conv folded
// into Q; barrier-free main loop, online softmax, no spill) -> proj.
//
// ws layout (bytes):
//   [0)          xbf   33,554,432  (x bf16; REUSED as attnout after gemm_qkv)
//   [33554432)   w1     1,572,864  (qkv_w bf16)
//   [35127296)   w2       524,288  (proj_w bf16)
//   [35651584)   qb    33,554,432  (q scaled (b,h,n,d); conv'd in place)
//   [69206016)   kb    33,554,432  ((b,h,m,d))
//   [102760448)  vb    33,554,432  (V row-major (b,h,n,d))

typedef unsigned short u16;
typedef unsigned int u32;
typedef __attribute__((ext_vector_type(8))) short short8;   // 8 bf16 (4 VGPRs)
typedef __attribute__((ext_vector_type(4))) float f32x4;

__device__ __forceinline__ u16 f2bf(float f) {
  union { float f; u32 u; } v; v.f = f;
  return (u16)((v.u + 0x7FFFu + ((v.u >> 16) & 1u)) >> 16);  // RNE
}
__device__ __forceinline__ float bf2f(u16 s) {
  union { u32 u; float f; } v; v.u = ((u32)s) << 16;
  return v.f;
}

__device__ __forceinline__ void gl2lds16(const u16* g, u16* l) {
  __builtin_amdgcn_global_load_lds((const __attribute__((address_space(1))) void*)g,
                                   (__attribute__((address_space(3))) void*)l, 16, 0, 0);
}

// fragment cell address (u16 units) with bank-spreading XOR swizzle
__device__ __forceinline__ int fragaddr(int frag, int lane) {
  return (frag * 64 + (lane ^ (frag & 7))) * 8;
}

// ---------------- fp32 -> bf16 conversion ------------------------------------
__global__ __launch_bounds__(256) void cvt_all(
    const float* __restrict__ x, const float* __restrict__ w1f,
    const float* __restrict__ w2f, u16* __restrict__ xo,
    u16* __restrict__ w1o, u16* __restrict__ w2o) {
  const int NX = 4194304, NW1 = 196608, NW2 = 65536;
  int i = blockIdx.x * 256 + threadIdx.x;
  const float* src; u16* dst; int j;
  if (i < NX)                  { src = x;   dst = xo;  j = i; }
  else if (i < NX + NW1)       { src = w1f; dst = w1o; j = i - NX; }
  else if (i < NX + NW1 + NW2) { src = w2f; dst = w2o; j = i - NX - NW1; }
  else return;
  float4 f = ((const float4*)src)[j];
  uint2 o;
  o.x = (u32)f2bf(f.x) | ((u32)f2bf(f.y) << 16);
  o.y = (u32)f2bf(f.z) | ((u32)f2bf(f.w) << 16);
  ((uint2*)dst)[j] = o;
}

// ---------------- shared GEMM core: C[128x128] = A[128xK] * B[128xK]^T -------
template <int KDIM>
__device__ __forceinline__ void gemm_core(const u16* __restrict__ A,
                                          const u16* __restrict__ B,
                                          int m0, int n0,
                                          u16* As, u16* Bs, f32x4 acc[4][4]) {
  int tid = threadIdx.x, wave = tid >> 6, lane = tid & 63;
  int wm = wave >> 1, wn = wave & 1;
  int lr = lane >> 3, lc = (lane & 7) * 8;
  const u16* Ag = A + (size_t)(m0 + wave * 32 + lr) * KDIM + lc;
  const u16* Bg = B + (size_t)(n0 + wave * 32 + lr) * KDIM + lc;
  u16* AsW = As + wave * 32 * 64;
  u16* BsW = Bs + wave * 32 * 64;
  for (int k0 = 0; k0 < KDIM; k0 += 64) {
#pragma unroll
    for (int it = 0; it < 4; ++it) {
      gl2lds16(Ag + k0 + it * 8 * KDIM, AsW + it * 8 * 64);
      gl2lds16(Bg + k0 + it * 8 * KDIM, BsW + it * 8 * 64);
    }
    __syncthreads();
    int q8 = (lane >> 4) * 8;
#pragma unroll
    for (int ks = 0; ks < 64; ks += 32) {
      short8 af[4], bf8[4];
#pragma unroll
      for (int t = 0; t < 4; ++t) {
        af[t]  = *(const short8*)(As + (wm * 64 + t * 16 + (lane & 15)) * 64 + ks + q8);
        bf8[t] = *(const short8*)(Bs + (wn * 64 + t * 16 + (lane & 15)) * 64 + ks + q8);
      }
#pragma unroll
      for (int tm = 0; tm < 4; ++tm)
#pragma unroll
        for (int tn = 0; tn < 4; ++tn)
          acc[tm][tn] = __builtin_amdgcn_mfma_f32_16x16x32_bf16(
              af[tm], bf8[tn], acc[tm][tn], 0, 0, 0);
    }
    __syncthreads();
  }
}

// ---------------- GEMM1: qkv = x @ qkv_w^T + b; scatter q(scaled)/k/v --------
__global__ __launch_bounds__(256) void gemm_qkv(
    const u16* __restrict__ A, const u16* __restrict__ B,
    const float* __restrict__ qkvb, u16* __restrict__ qb,
    u16* __restrict__ kb, u16* __restrict__ vb) {
  __shared__ __align__(16) u16 As[128 * 64];
  __shared__ __align__(16) u16 Bs[128 * 64];
  f32x4 acc[4][4];
#pragma unroll
  for (int a = 0; a < 4; ++a)
#pragma unroll
    for (int c = 0; c < 4; ++c) acc[a][c] = (f32x4){0.f, 0.f, 0.f, 0.f};
  int m0 = blockIdx.x * 128, n0 = blockIdx.y * 128;
  gemm_core<512>(A, B, m0, n0, As, Bs, acc);
  int tid = threadIdx.x, wave = tid >> 6, lane = tid & 63;
  int wm = wave >> 1, wn = wave & 1;
#pragma unroll
  for (int tm = 0; tm < 4; ++tm) {
    int rbase = m0 + wm * 64 + tm * 16 + (lane >> 4) * 4;
#pragma unroll
    for (int tn = 0; tn < 4; ++tn) {
      int c = n0 + wn * 64 + tn * 16 + (lane & 15);
      float bv = qkvb[c];
      int which = c >> 9, cc = c & 511;
      int h = cc >> 6, d = cc & 63;
#pragma unroll
      for (int i = 0; i < 4; ++i) {
        int r = rbase + i;
        int b = r >> 8, n = r & 255;
        float v = acc[tm][tn][i] + bv;
        size_t idx = ((size_t)(b * 8 + h) * 256 + n) * 64 + d;
        if (which == 0)      qb[idx] = f2bf(v * 0.125f);
        else if (which == 1) kb[idx] = f2bf(v);
        else                 vb[idx] = f2bf(v);
      }
    }
  }
}

// ---------------- qconv: Q' = Q + conv15_n(Q), in place per (b,h) window -----
__global__ __launch_bounds__(256) void qconv(u16* __restrict__ qb,
                                             const float* __restrict__ pe_w) {
  __shared__ __align__(16) u16 Ql[256 * 72];
  __shared__ float w[15];
  int bh = blockIdx.x, h = bh & 7, tid = threadIdx.x;
  const uint4* src = (const uint4*)(qb + (size_t)bh * 16384);
#pragma unroll
  for (int it = 0; it < 8; ++it) {
    int idx = tid + it * 256;
    int row = idx >> 3, c = (idx & 7) * 8;
    *(uint4*)(Ql + row * 72 + c) = src[idx];
  }
  if (tid < 15) w[tid] = pe_w[h * 15 + tid] + (tid == 7 ? 1.f : 0.f);  // identity folded
  __syncthreads();
  int dg = (tid & 15) * 4, nb4 = tid >> 4;
  uint2* dst = (uint2*)(qb + (size_t)bh * 16384);
#pragma unroll
  for (int i = 0; i < 16; ++i) {
    int n = nb4 + i * 16;
    float a0 = 0.f, a1 = 0.f, a2 = 0.f, a3 = 0.f;
#pragma unroll
    for (int t = 0; t < 15; ++t) {
      int nn = n + t - 7;
      if (nn < 0 || nn > 255) continue;
      uint2 rv = *(const uint2*)(Ql + nn * 72 + dg);
      float wt = w[t];
      a0 += wt * bf2f(rv.x & 0xffff); a1 += wt * bf2f(rv.x >> 16);
      a2 += wt * bf2f(rv.y & 0xffff); a3 += wt * bf2f(rv.y >> 16);
    }
    uint2 pv;
    pv.x = (u32)f2bf(a0) | ((u32)f2bf(a1) << 16);
    pv.y = (u32)f2bf(a2) | ((u32)f2bf(a3) << 16);
    dst[(n * 64 + dg) >> 2] = pv;
  }
}

// ---------------- attention: 1 wg (512 thr) per (b,h); barrier-free loop -----
// LDS: KfPs 42K (Kf 32K + Ps 10K; doubles as Vtmp during staging) + Vf 32K +
// bias 3.8K = ~79.6K -> 2 wg/CU. Online softmax over 2 column halves keeps
// regs ~100 (no spill; launch_bounds(512,2) cannot force one).
__global__ __launch_bounds__(512, 2) void attn_win(
    const u16* __restrict__ qb, const u16* __restrict__ kb,
    const u16* __restrict__ vb, const float* __restrict__ pe_b,
    const float* __restrict__ rpb, u16* __restrict__ attnout) {
  __shared__ __align__(16) u16 KfPs[21504];   // [0,16384)=Kf, [16384,21504)=Ps
  __shared__ __align__(16) u16 Vf[16384];     // 32 frags (dt,km), fragment-ordered
  __shared__ float biasl[961];
  __shared__ float pebs;

  int bh = blockIdx.x, b = bh >> 3, h = bh & 7;
  int tid = threadIdx.x, wave = tid >> 6, lane = tid & 63;
  int cx = lane & 15, g = lane >> 4;

  const uint4* kg = (const uint4*)(kb + (size_t)bh * 16384);
  const uint4* vg = (const uint4*)(vb + (size_t)bh * 16384);

  // K prefetch into registers (Kf region is occupied by Vtmp until Vf built)
  uint4 kreg[4];
#pragma unroll
  for (int it = 0; it < 4; ++it) kreg[it] = kg[tid + it * 512];

  // ---- stage V rows -> Vtmp (stride 68, bank-spread) + bias ----
  u16* Vtmp = KfPs;
#pragma unroll
  for (int it = 0; it < 4; ++it) {
    int idx = tid + it * 512;
    uint4 v = vg[idx];
    int row = idx >> 3, c8 = (idx & 7) * 8;
    *(uint2*)(Vtmp + row * 68 + c8)     = make_uint2(v.x, v.y);
    *(uint2*)(Vtmp + row * 68 + c8 + 4) = make_uint2(v.z, v.w);
  }
  for (int i = tid; i < 961; i += 512) biasl[i] = rpb[i * 8 + h];
  if (tid == 0) pebs = pe_b[h];
  __syncthreads();

  // ---- build Vf fragments (transpose): frag(dt,km), lane holds V[m..m+7][d] --
#pragma unroll
  for (int it = 0; it < 4; ++it) {
    int o = tid + it * 512;
    int frag = o >> 6, lanep = o & 63;
    int d = (frag >> 3) * 16 + (lanep & 15);
    int mb = (frag & 7) * 32 + (lanep >> 4) * 8;
    uint4 pk;
    pk.x = (u32)Vtmp[(mb + 0) * 68 + d] | ((u32)Vtmp[(mb + 1) * 68 + d] << 16);
    pk.y = (u32)Vtmp[(mb + 2) * 68 + d] | ((u32)Vtmp[(mb + 3) * 68 + d] << 16);
    pk.z = (u32)Vtmp[(mb + 4) * 68 + d] | ((u32)Vtmp[(mb + 5) * 68 + d] << 16);
    pk.w = (u32)Vtmp[(mb + 6) * 68 + d] | ((u32)Vtmp[(mb + 7) * 68 + d] << 16);
    *(uint4*)(Vf + (frag * 64 + (lanep ^ (frag & 7))) * 8) = pk;
  }
  __syncthreads();

  // ---- write K fragments from registers ----
  u16* Kf = KfPs;
#pragma unroll
  for (int it = 0; it < 4; ++it) {
    int idx = tid + it * 512;
    int n = idx >> 3, k8 = idx & 7;
    int frag = (n >> 4) * 2 + (k8 >> 2);
    int lanep = (n & 15) + 16 * (k8 & 3);
    *(uint4*)(Kf + (frag * 64 + (lanep ^ (frag & 7))) * 8) = kreg[it];
  }
  __syncthreads();   // last barrier — main loop is barrier-free

  u16* Psw = KfPs + 16384 + wave * 640;
  const u16* qgb = qb + (size_t)bh * 16384;

  for (int it2 = 0; it2 < 2; ++it2) {
    int qbase = it2 * 128 + wave * 16;
    const u16* qg = qgb + qbase * 64;
    short8 qf0 = *(const short8*)(qg + cx * 64 + g * 8);
    short8 qf1 = *(const short8*)(qg + cx * 64 + 32 + g * 8);

    float m_run[4] = {-1e30f, -1e30f, -1e30f, -1e30f};
    float l_run[4] = {0.f, 0.f, 0.f, 0.f};
    f32x4 oacc[4];
#pragma unroll
    for (int dt = 0; dt < 4; ++dt) oacc[dt] = (f32x4){0.f, 0.f, 0.f, 0.f};

#pragma unroll
    for (int c = 0; c < 2; ++c) {
      // ---- QK^T over this 128-column half ----
      f32x4 acc[8];
#pragma unroll
      for (int mt = 0; mt < 8; ++mt) acc[mt] = (f32x4){0.f, 0.f, 0.f, 0.f};
#pragma unroll
      for (int mt = 0; mt < 8; ++mt) {
        int fr = (c * 8 + mt) * 2;
        short8 k0 = *(const short8*)(Kf + fragaddr(fr, lane));
        short8 k1 = *(const short8*)(Kf + fragaddr(fr + 1, lane));
        acc[mt] = __builtin_amdgcn_mfma_f32_16x16x32_bf16(qf0, k0, acc[mt], 0, 0, 0);
        acc[mt] = __builtin_amdgcn_mfma_f32_16x16x32_bf16(qf1, k1, acc[mt], 0, 0, 0);
      }

      // ---- bias + online softmax update (in-wave, no barriers) ----
      float alpha4[4];
#pragma unroll
      for (int i = 0; i < 4; ++i) {
        int qtok = qbase + g * 4 + i;
        int bbase = ((qtok >> 4) - c * 8 + 15) * 31 + (qtok & 15) - cx + 15;
#pragma unroll
        for (int mt = 0; mt < 8; ++mt) acc[mt][i] += pebs + biasl[bbase - 31 * mt];
        float mx = acc[0][i];
#pragma unroll
        for (int mt = 1; mt < 8; ++mt) mx = fmaxf(mx, acc[mt][i]);
        mx = fmaxf(mx, __shfl_xor(mx, 1));
        mx = fmaxf(mx, __shfl_xor(mx, 2));
        mx = fmaxf(mx, __shfl_xor(mx, 4));
        mx = fmaxf(mx, __shfl_xor(mx, 8));
        float mnew = fmaxf(m_run[i], mx);
        float al = __expf(m_run[i] - mnew);
        float s = 0.f;
#pragma unroll
        for (int mt = 0; mt < 8; ++mt) {
          float e = __expf(acc[mt][i] - mnew);
          acc[mt][i] = e; s += e;
        }
        s += __shfl_xor(s, 1);
        s += __shfl_xor(s, 2);
        s += __shfl_xor(s, 4);
        s += __shfl_xor(s, 8);
        l_run[i] = l_run[i] * al + s;
        m_run[i] = mnew;
        alpha4[i] = al;
      }
#pragma unroll
      for (int dt = 0; dt < 4; ++dt)
#pragma unroll
        for (int i = 0; i < 4; ++i) oacc[dt][i] *= alpha4[i];

      // ---- PV via per-wave scratch (in-wave LDS ordering) ----
#pragma unroll
      for (int kk = 0; kk < 4; ++kk) {
#pragma unroll
        for (int t2 = 0; t2 < 2; ++t2)
#pragma unroll
          for (int i = 0; i < 4; ++i)
            Psw[(g * 4 + i) * 40 + t2 * 16 + cx] = f2bf(acc[kk * 2 + t2][i]);
        short8 pa = *(const short8*)(Psw + cx * 40 + g * 8);
#pragma unroll
        for (int dt = 0; dt < 4; ++dt) {
          short8 vf = *(const short8*)(Vf + fragaddr(dt * 8 + c * 4 + kk, lane));
          oacc[dt] = __builtin_amdgcn_mfma_f32_16x16x32_bf16(pa, vf, oacc[dt], 0, 0, 0);
        }
      }
    }

    // ---- epilogue: normalize + store ----
    float inv4[4];
#pragma unroll
    for (int i = 0; i < 4; ++i) inv4[i] = 1.f / l_run[i];
#pragma unroll
    for (int dt = 0; dt < 4; ++dt)
#pragma unroll
      for (int i = 0; i < 4; ++i)
        attnout[((size_t)b * 256 + qbase + g * 4 + i) * 512 + h * 64 + dt * 16 + cx]
            = f2bf(oacc[dt][i] * inv4[i]);
  }
}

// ---------------- GEMM2: out = attnout @ proj_w^T + proj_b (fp32 out) --------
__global__ __launch_bounds__(256) void gemm_proj(
    const u16* __restrict__ A, const u16* __restrict__ B,
    const float* __restrict__ pb, float* __restrict__ out) {
  __shared__ __align__(16) u16 As[128 * 64];
  __shared__ __align__(16) u16 Bs[128 * 64];
  f32x4 acc[4][4];
#pragma unroll
  for (int a = 0; a < 4; ++a)
#pragma unroll
    for (int c = 0; c < 4; ++c) acc[a][c] = (f32x4){0.f, 0.f, 0.f, 0.f};
  int m0 = blockIdx.x * 128, n0 = blockIdx.y * 128;
  gemm_core<512>(A, B, m0, n0, As, Bs, acc);
  int tid = threadIdx.x, wave = tid >> 6, lane = tid & 63;
  int wm = wave >> 1, wn = wave & 1;
#pragma unroll
  for (int tm = 0; tm < 4; ++tm) {
    int rbase = m0 + wm * 64 + tm * 16 + (lane >> 4) * 4;
#pragma unroll
    for (int tn = 0; tn < 4; ++tn) {
      int c = n0 + wn * 64 + tn * 16 + (lane & 15);
      float bv = pb[c];
#pragma unroll
      for (int i = 0; i < 4; ++i)
        out[(size_t)(rbase + i) * 512 + c] = acc[tm][tn][i] + bv;
    }
  }
}

extern "C" void kernel_launch(void* const* d_in, const int* in_sizes, int n_in,
                              void* d_out, int out_size, void* d_ws, size_t ws_size,
                              hipStream_t stream) {
  const float* x      = (const float*)d_in[0];
  const float* qkv_w  = (const float*)d_in[1];
  const float* qkv_b  = (const float*)d_in[2];
  const float* pe_w   = (const float*)d_in[3];
  const float* pe_b   = (const float*)d_in[4];
  const float* rpb    = (const float*)d_in[5];
  const float* proj_w = (const float*)d_in[6];
  const float* proj_b = (const float*)d_in[7];
  float* out = (float*)d_out;
  char* ws = (char*)d_ws;

  size_t off = 0;
  u16* xbf = (u16*)(ws + off); off += (size_t)16777216 * 2;  // also attnout
  u16* w1  = (u16*)(ws + off); off += (size_t)786432 * 2;
  u16* w2  = (u16*)(ws + off); off += (size_t)262144 * 2;
  u16* qb  = (u16*)(ws + off); off += (size_t)16777216 * 2;
  u16* kb  = (u16*)(ws + off); off += (size_t)16777216 * 2;
  u16* vb  = (u16*)(ws + off); off += (size_t)16777216 * 2;

  hipLaunchKernelGGL(cvt_all, dim3(17408), dim3(256), 0, stream,
                     x, qkv_w, proj_w, xbf, w1, w2);
  hipLaunchKernelGGL(gemm_qkv, dim3(256, 12), dim3(256), 0, stream,
                     xbf, w1, qkv_b, qb, kb, vb);
  hipLaunchKernelGGL(qconv, dim3(1024), dim3(256), 0, stream, qb, pe_w);
  hipLaunchKernelGGL(attn_win, dim3(1024), dim3(512), 0, stream,
                     qb, kb, vb, pe_b, rpb, xbf);
  hipLaunchKernelGGL(gemm_proj, dim3(256, 4), dim3(256), 0, stream,
                     xbf, w2, proj_b, out);
}